// Round 5
// baseline (869.106 us; speedup 1.0000x reference)
//
#include <hip/hip_runtime.h>
#include <stdint.h>
#include <math.h>

typedef __attribute__((ext_vector_type(8))) short short8;
typedef __attribute__((ext_vector_type(4))) float f32x4;
typedef __attribute__((ext_vector_type(4))) int i32x4;

namespace {
constexpr int Hh = 64, Ss = 362, Dd = 506, NQT = 12;
constexpr int KQS = 40;   // Q/K LDS row stride, bf16 elems (80B)
constexpr int PKW = 68;   // pk row stride, u32 words (272B)
constexpr int VTS = 72;   // vt row stride, bf16 elems (144B; %8==0 for b128 alignment)
}

struct P1 { unsigned short qhi[32*KQS], qlo[32*KQS], khi[128*KQS], klo[128*KQS]; }; // 25600B
struct P3 { unsigned short vthi[64*VTS], vtlo[64*VTS]; unsigned int pk[32*PKW]; };  // 27136B
union SMEM { P1 p1; P3 p3; };

__device__ __forceinline__ uint32_t rotl32(uint32_t x, int d) {
  return (x << d) | (x >> (32 - d));
}

// JAX threefry2x32, partitionable path: counter=(0, idx), key=(0,42), out = x0^x1.
__device__ __forceinline__ uint32_t tf32_xor(uint32_t idx) {
  const uint32_t K0 = 0u, K1 = 42u, K2 = 0x1BD11BDAu ^ 0u ^ 42u;
  uint32_t x0 = 0u + K0;
  uint32_t x1 = idx + K1;
#define TF_R(a) { x0 += x1; x1 = rotl32(x1, (a)); x1 ^= x0; }
  TF_R(13) TF_R(15) TF_R(26) TF_R(6)
  x0 += K1; x1 += K2 + 1u;
  TF_R(17) TF_R(29) TF_R(16) TF_R(24)
  x0 += K2; x1 += K0 + 2u;
  TF_R(13) TF_R(15) TF_R(26) TF_R(6)
  x0 += K0; x1 += K1 + 3u;
  TF_R(17) TF_R(29) TF_R(16) TF_R(24)
  x0 += K1; x1 += K2 + 4u;
  TF_R(13) TF_R(15) TF_R(26) TF_R(6)
  x0 += K2; x1 += K0 + 5u;
#undef TF_R
  return x0 ^ x1;
}

// Split floats a,b into packed bf16-hi word (hi(a)|hi(b)<<16) and bf16-lo word.
// Truncation split: hi+lo == x exactly; dropped lo*lo term ~2^-16 rel.
__device__ __forceinline__ void splitpk(float a, float b, unsigned& hw, unsigned& lw) {
  unsigned ua = __float_as_uint(a), ub = __float_as_uint(b);
  unsigned ha = ua & 0xffff0000u, hb = ub & 0xffff0000u;
  float la = a - __uint_as_float(ha);
  float lb = b - __uint_as_float(hb);
  hw = (ha >> 16) | hb;
  lw = (__float_as_uint(la) >> 16) | (__float_as_uint(lb) & 0xffff0000u);
}

// Pack one float as (bf16hi | bf16lo<<16).
__device__ __forceinline__ unsigned packp(float p) {
  unsigned up = __float_as_uint(p);
  unsigned hp = up & 0xffff0000u;
  float lp = p - __uint_as_float(hp);
  return (hp >> 16) | (__float_as_uint(lp) & 0xffff0000u);
}

__global__ __launch_bounds__(256, 2)
void fa_mfma_kernel(const float* __restrict__ Q, const float* __restrict__ K,
                    const float* __restrict__ V, const float* __restrict__ Msk,
                    float* __restrict__ O) {
  __shared__ SMEM sm;
  __shared__ float redscr[64];

  const int tid = threadIdx.x;
  const int nwg = Hh * NQT;                       // 768, %8==0 -> simple bijective swizzle
  const int swz = ((int)blockIdx.x & 7) * (nwg >> 3) + ((int)blockIdx.x >> 3);
  const int h = swz / NQT, qt = swz % NQT;
  const int q0 = qt * 32;

  const int w = tid >> 6, lane = tid & 63;
  const int wr = w >> 1, wc = w & 1;              // row-tile, col-half of this wave
  const int lg = lane >> 4, ln = lane & 15;

  const float scale = 1.0f / sqrtf(506.0f);

  const float* Qh = Q + (size_t)h * Ss * Dd;
  const float* Kh = K + (size_t)h * Ss * Dd;
  const float* Vh = V + (size_t)h * Ss * Dd;
  float*       Oh = O + (size_t)h * Ss * Dd;

  unsigned* qhw = (unsigned*)sm.p1.qhi;
  unsigned* qlw = (unsigned*)sm.p1.qlo;
  unsigned* khw = (unsigned*)sm.p1.khi;
  unsigned* klw = (unsigned*)sm.p1.klo;

  // ================= Phase 1: S = (Q*scale) K^T via split-bf16 MFMA =================
  // acc[kt*4+nf]: C rows = q0 + wr*16 + lg*4 + r (m89 layout), cols = kt*128 + wc*64 + nf*16 + ln
  f32x4 acc[12];
#pragma unroll
  for (int f = 0; f < 12; ++f) acc[f] = (f32x4)(0.0f);

  for (int dk = 0; dk < 512; dk += 32) {
    // stage Q chunk 32x32 (scale folded), paired-u32 writes
#pragma unroll
    for (int it = 0; it < 2; ++it) {
      int lin = it * 256 + tid;
      int row = lin >> 4, dh = lin & 15;
      int q = q0 + row, d = dk + dh * 2;
      float a = 0.f, b = 0.f;
      if (q < Ss && d < Dd) {
        float2 v = *(const float2*)(Qh + (size_t)q * Dd + d);
        a = v.x * scale; b = v.y * scale;
      }
      unsigned hw, lw; splitpk(a, b, hw, lw);
      qhw[row * 20 + dh] = hw; qlw[row * 20 + dh] = lw;
    }
#pragma unroll
    for (int kt = 0; kt < 3; ++kt) {
      // stage K tile 128x32
#pragma unroll
      for (int it = 0; it < 8; ++it) {
        int lin = it * 256 + tid;
        int row = lin >> 4, dh = lin & 15;
        int kk = kt * 128 + row, d = dk + dh * 2;
        float a = 0.f, b = 0.f;
        if (kk < Ss && d < Dd) {
          float2 v = *(const float2*)(Kh + (size_t)kk * Dd + d);
          a = v.x; b = v.y;
        }
        unsigned hw, lw; splitpk(a, b, hw, lw);
        khw[row * 20 + dh] = hw; klw[row * 20 + dh] = lw;
      }
      __syncthreads();
      short8 aH = *(const short8*)&sm.p1.qhi[(wr * 16 + ln) * KQS + lg * 8];
      short8 aL = *(const short8*)&sm.p1.qlo[(wr * 16 + ln) * KQS + lg * 8];
#pragma unroll
      for (int nf = 0; nf < 4; ++nf) {
        int krow = wc * 64 + nf * 16 + ln;
        short8 bH = *(const short8*)&sm.p1.khi[krow * KQS + lg * 8];
        short8 bL = *(const short8*)&sm.p1.klo[krow * KQS + lg * 8];
        acc[kt*4+nf] = __builtin_amdgcn_mfma_f32_16x16x32_bf16(aH, bH, acc[kt*4+nf], 0, 0, 0);
        acc[kt*4+nf] = __builtin_amdgcn_mfma_f32_16x16x32_bf16(aH, bL, acc[kt*4+nf], 0, 0, 0);
        acc[kt*4+nf] = __builtin_amdgcn_mfma_f32_16x16x32_bf16(aL, bH, acc[kt*4+nf], 0, 0, 0);
      }
      __syncthreads();
    }
  }

  // ================= Phase 2: mask + softmax + threefry dropout (in registers) ======
#pragma unroll
  for (int f = 0; f < 12; ++f) {
    int kt = f >> 2, nf = f & 3;
    int cb = kt * 128 + wc * 64 + nf * 16 + ln;
#pragma unroll
    for (int r = 0; r < 4; ++r) {
      int q = q0 + wr * 16 + lg * 4 + r;
      float s;
      if (cb < Ss) {
        float mk = (q < Ss) ? Msk[q * Ss + cb] : 0.f;
        s = acc[f][r] + mk;
      } else s = -INFINITY;
      acc[f][r] = s;
    }
  }
  float mrow[4];
#pragma unroll
  for (int r = 0; r < 4; ++r) {
    float m = acc[0][r];
#pragma unroll
    for (int f = 1; f < 12; ++f) m = fmaxf(m, acc[f][r]);
#pragma unroll
    for (int off = 1; off < 16; off <<= 1) m = fmaxf(m, __shfl_xor(m, off, 64));
    mrow[r] = m;
  }
  if (ln < 4) redscr[w * 16 + lg * 4 + ln] = mrow[ln];
  __syncthreads();
#pragma unroll
  for (int r = 0; r < 4; ++r) mrow[r] = fmaxf(mrow[r], redscr[(w ^ 1) * 16 + lg * 4 + r]);
  __syncthreads();
  float srow[4] = {0.f, 0.f, 0.f, 0.f};
#pragma unroll
  for (int f = 0; f < 12; ++f)
#pragma unroll
    for (int r = 0; r < 4; ++r) {
      float e = __expf(acc[f][r] - mrow[r]);
      acc[f][r] = e;
      srow[r] += e;
    }
#pragma unroll
  for (int r = 0; r < 4; ++r)
#pragma unroll
    for (int off = 1; off < 16; off <<= 1) srow[r] += __shfl_xor(srow[r], off, 64);
  if (ln < 4) redscr[w * 16 + lg * 4 + ln] = srow[ln];
  __syncthreads();
#pragma unroll
  for (int r = 0; r < 4; ++r) srow[r] = 1.0f / (srow[r] + redscr[(w ^ 1) * 16 + lg * 4 + r]);

  unsigned preg[12][4];                            // P packed (bf16hi | bf16lo<<16)
#pragma unroll
  for (int f = 0; f < 12; ++f) {
    int kt = f >> 2, nf = f & 3;
    int cb = kt * 128 + wc * 64 + nf * 16 + ln;
#pragma unroll
    for (int r = 0; r < 4; ++r) {
      int q = q0 + wr * 16 + lg * 4 + r;
      float p = 0.f;
      if (q < Ss && cb < Ss) {
        p = acc[f][r] * srow[r];
        unsigned idx = ((unsigned)h * (unsigned)Ss + (unsigned)q) * (unsigned)Ss + (unsigned)cb;
        unsigned bits = tf32_xor(idx);
        float u = __uint_as_float((bits >> 9) | 0x3f800000u) - 1.0f;
        p = (u < 0.9f) ? p * (1.0f / 0.9f) : 0.f;
      }
      preg[f][r] = packp(p);
    }
  }

  // ================= Phase 3: O = P V via split-bf16 MFMA, LDS-transposed V =========
  f32x4 oacc[8][2];
#pragma unroll
  for (int dt = 0; dt < 8; ++dt) { oacc[dt][0] = (f32x4)(0.0f); oacc[dt][1] = (f32x4)(0.0f); }

  unsigned* vthw = (unsigned*)sm.p3.vthi;
  unsigned* vtlw = (unsigned*)sm.p3.vtlo;

  for (int kc = 0; kc < 6; ++kc) {
    // publish this key-chunk's P columns (owned by waves with matching col-half)
    if (wc == (kc & 1)) {
#pragma unroll
      for (int f = 0; f < 12; ++f) {
        if ((f >> 2) == (kc >> 1)) {
          int nf = f & 3;
#pragma unroll
          for (int r = 0; r < 4; ++r) {
            int row = wr * 16 + lg * 4 + r;
            sm.p3.pk[row * PKW + nf * 16 + ln] = preg[f][r];
          }
        }
      }
    }
    __syncthreads();
#pragma unroll
    for (int dt = 0; dt < 8; ++dt) {
      // stage V^T chunk: vt[d_local][k_local], 64x64, paired-u32 k writes
#pragma unroll
      for (int it = 0; it < 4; ++it) {
        int lin = it * 256 + tid;
        int dp = lin & 31;                 // d-pair 0..31 (coalesced within wave)
        int kq = lin >> 5;                 // k-pair 0..31
        int dloc = dp * 2;
        int dglob = dt * 64 + dloc;
        int kglob = kc * 64 + kq * 2;
        float2 va = make_float2(0.f, 0.f), vb = make_float2(0.f, 0.f);
        if (dglob < Dd) {
          if (kglob < Ss)     va = *(const float2*)(Vh + (size_t)kglob * Dd + dglob);
          if (kglob + 1 < Ss) vb = *(const float2*)(Vh + (size_t)(kglob + 1) * Dd + dglob);
        }
        unsigned hwx, lwx, hwy, lwy;
        splitpk(va.x, vb.x, hwx, lwx);     // column dglob,   keys kglob,kglob+1
        splitpk(va.y, vb.y, hwy, lwy);     // column dglob+1
        vthw[dloc * 36 + kq]       = hwx;
        vtlw[dloc * 36 + kq]       = lwx;
        vthw[(dloc + 1) * 36 + kq] = hwy;
        vtlw[(dloc + 1) * 36 + kq] = lwy;
      }
      __syncthreads();
#pragma unroll
      for (int ks = 0; ks < 2; ++ks) {
        // A = P fragment: row = wr*16+ln, k = ks*32 + lg*8 + j  (u32 per key col)
        const unsigned* prow = &sm.p3.pk[(wr * 16 + ln) * PKW + ks * 32 + lg * 8];
        i32x4 pa = *(const i32x4*)prow;
        i32x4 pb = *(const i32x4*)(prow + 4);
        i32x4 ah, al;
        ah.x = (pa.x & 0xffff) | (pa.y << 16);
        ah.y = (pa.z & 0xffff) | (pa.w << 16);
        ah.z = (pb.x & 0xffff) | (pb.y << 16);
        ah.w = (pb.z & 0xffff) | (pb.w << 16);
        al.x = (int)(((unsigned)pa.x >> 16) | ((unsigned)pa.y & 0xffff0000u));
        al.y = (int)(((unsigned)pa.z >> 16) | ((unsigned)pa.w & 0xffff0000u));
        al.z = (int)(((unsigned)pb.x >> 16) | ((unsigned)pb.y & 0xffff0000u));
        al.w = (int)(((unsigned)pb.z >> 16) | ((unsigned)pb.w & 0xffff0000u));
        short8 aH = __builtin_bit_cast(short8, ah);
        short8 aL = __builtin_bit_cast(short8, al);
#pragma unroll
        for (int nf = 0; nf < 2; ++nf) {
          // B = V^T fragment: n-col = d_local = wc*32+nf*16+ln, k = ks*32+lg*8+j
          int dloc = wc * 32 + nf * 16 + ln;
          short8 vH = *(const short8*)&sm.p3.vthi[dloc * VTS + ks * 32 + lg * 8];
          short8 vL = *(const short8*)&sm.p3.vtlo[dloc * VTS + ks * 32 + lg * 8];
          oacc[dt][nf] = __builtin_amdgcn_mfma_f32_16x16x32_bf16(aH, vH, oacc[dt][nf], 0, 0, 0);
          oacc[dt][nf] = __builtin_amdgcn_mfma_f32_16x16x32_bf16(aH, vL, oacc[dt][nf], 0, 0, 0);
          oacc[dt][nf] = __builtin_amdgcn_mfma_f32_16x16x32_bf16(aL, vH, oacc[dt][nf], 0, 0, 0);
        }
      }
      __syncthreads();
    }
  }

  // ================= Epilogue =================
#pragma unroll
  for (int dt = 0; dt < 8; ++dt)
#pragma unroll
    for (int nf = 0; nf < 2; ++nf) {
      int d = dt * 64 + wc * 32 + nf * 16 + ln;
      if (d < Dd) {
#pragma unroll
        for (int r = 0; r < 4; ++r) {
          int q = q0 + wr * 16 + lg * 4 + r;
          if (q < Ss) Oh[(size_t)q * Dd + d] = oacc[dt][nf][r];
        }
      }
    }
}

extern "C" void kernel_launch(void* const* d_in, const int* in_sizes, int n_in,
                              void* d_out, int out_size, void* d_ws, size_t ws_size,
                              hipStream_t stream) {
  const float* Q   = (const float*)d_in[0];
  const float* K   = (const float*)d_in[1];
  const float* V   = (const float*)d_in[2];
  const float* Msk = (const float*)d_in[3];
  float* O = (float*)d_out;
  (void)in_sizes; (void)n_in; (void)out_size; (void)d_ws; (void)ws_size;
  fa_mfma_kernel<<<dim3(Hh * NQT), 256, 0, stream>>>(Q, K, V, Msk, O);
}